// Round 12
// baseline (14869.353 us; speedup 1.0000x reference)
//
#include <hip/hip_runtime.h>
#include <hip/hip_bf16.h>

// GRU: B=64, T=2048, D=H=O=1024.
// Path A: xp = x@Wx^T precomputed (barrier-free bf16 GEMM, xp_gemm2), then
// h-only persistent scan = EXACT round-7 structure (best measured: 8.1 ms):
//   256 blocks x 512 thr (1 blk/CU via LDS>100KB). g=bid&7 -> 8 batch rows,
//   c=bid>>3 -> 32 columns. Dual-publish h: L2 copy (plain store, sc0 batched
//   hammer poll) + MALL copy (agent store, sticky fallback after 256 spins).
//   Tag-in-value sync (LSB parity), 2-slot ring, two barriers per step.
// xp_gemm2: no LDS, no barriers — waves independent, A-frags straight from
// global x (same lane mapping as the verified staged version), B-frags from
// MALL-resident Wxb. Fallback (small ws): round-2 ring kernel.

#define Bb 64
#define Tt 2048
#define Dd 1024
#define Hh 1024

typedef __attribute__((ext_vector_type(8))) short bf16x8;
typedef __attribute__((ext_vector_type(4))) float f32x4;

__device__ __forceinline__ short f2bf(float x) {
    __hip_bfloat16 h = __float2bfloat16(x);
    return __builtin_bit_cast(short, h);
}
__device__ __forceinline__ float bf2f(unsigned short u) {
    return __builtin_bit_cast(float, (unsigned)u << 16);
}
__device__ __forceinline__ bf16x8 pack8(float4 a, float4 b) {
    bf16x8 f;
    f[0] = f2bf(a.x); f[1] = f2bf(a.y); f[2] = f2bf(a.z); f[3] = f2bf(a.w);
    f[4] = f2bf(b.x); f[5] = f2bf(b.y); f[6] = f2bf(b.z); f[7] = f2bf(b.w);
    return f;
}
__device__ __forceinline__ unsigned long long ald64(const void* p) {
    return __hip_atomic_load((const unsigned long long*)p, __ATOMIC_RELAXED,
                             __HIP_MEMORY_SCOPE_AGENT);
}
__device__ __forceinline__ unsigned aldu32(const unsigned* p) {
    return __hip_atomic_load(p, __ATOMIC_RELAXED, __HIP_MEMORY_SCOPE_AGENT);
}

// ---------------- fp32 -> bf16 convert (weights) ------------------------------
__global__ void wcvt(const float* __restrict__ a, unsigned short* __restrict__ o, long n) {
    long i = ((long)blockIdx.x * blockDim.x + threadIdx.x) * 8;
    long stride = (long)gridDim.x * blockDim.x * 8;
    for (; i < n; i += stride)
        *(bf16x8*)(o + i) = pack8(*(const float4*)(a + i), *(const float4*)(a + i + 4));
}

// ---------------- xp GEMM v2: barrier-free, wave-independent ------------------
// grid (24, Wc). wave w owns cols n0w..n0w+31; full K=1024 loop; A-frags
// loaded per-lane directly from global x (identical lane->(row,k) mapping as
// the verified LDS-staged version; C-store layout unchanged).
__global__ __launch_bounds__(256)
void xp_gemm2(const float* __restrict__ x, const unsigned short* __restrict__ Wxb,
              unsigned short* __restrict__ xp, int t0) {
    const int tid = threadIdx.x;
    const int wave = tid >> 6, l = tid & 63, lm = l & 15, lk = l >> 4;
    const int slot = blockIdx.y;
    const int t = t0 + slot;
    const int n0w = blockIdx.x * 128 + wave * 32;

    f32x4 acc[4][2] = {};
#pragma unroll 1
    for (int k0 = 0; k0 < 1024; k0 += 32) {
        bf16x8 bfr[2];
#pragma unroll
        for (int nt = 0; nt < 2; ++nt)
            bfr[nt] = *(const bf16x8*)(Wxb + (size_t)(n0w + nt * 16 + lm) * 1024 + k0 + lk * 8);
#pragma unroll
        for (int mt = 0; mt < 4; ++mt) {
            const float* p = x + ((size_t)(mt * 16 + lm) * Tt + t) * Dd + k0 + lk * 8;
            const bf16x8 af = pack8(*(const float4*)p, *(const float4*)(p + 4));
            acc[mt][0] = __builtin_amdgcn_mfma_f32_16x16x32_bf16(af, bfr[0], acc[mt][0], 0, 0, 0);
            acc[mt][1] = __builtin_amdgcn_mfma_f32_16x16x32_bf16(af, bfr[1], acc[mt][1], 0, 0, 0);
        }
    }
    // D[b = mt*16 + lk*4 + i][n = n0w + nt*16 + lm]  (same as verified version)
#pragma unroll
    for (int mt = 0; mt < 4; ++mt)
#pragma unroll
        for (int nt = 0; nt < 2; ++nt)
#pragma unroll
            for (int i = 0; i < 4; ++i) {
                const int b = mt * 16 + lk * 4 + i;
                const int n = n0w + nt * 16 + lm;
                xp[((size_t)slot * 64 + b) * 3072 + n] = (unsigned short)f2bf(acc[mt][nt][i]);
            }
}

// ---------------- dual-publish h-only persistent scan (EXACT round 7) ---------
// 256 blocks x 512 thr, 1 blk/CU. g=bid&7: batch rows 8g..8g+7;
// c=bid>>3: columns [c*32,c*32+32). Wave w: K-slice [w*128,w*128+128).
// hl2 / hmall: [slot 2][group 8][row 8][col 1024] bf16 each.
__global__ __launch_bounds__(512, 2)
void gru_scan6(const float* __restrict__ Wh, const float* __restrict__ bx,
               const float* __restrict__ bh, unsigned short* __restrict__ hl2,
               unsigned short* __restrict__ hmall,
               float* __restrict__ hstate, float* __restrict__ hfinal,
               const unsigned short* __restrict__ xp, int t0, int tend) {
    const int tid = threadIdx.x;
    const int w = tid >> 6, l = tid & 63, lm = l & 15, lk = l >> 4;
    const int bid = blockIdx.x;
    const int g = bid & 7, c = bid >> 3;
    const int bg0 = g * 8, j0 = c * 32;
    const int kb = w * 128;

    __shared__ float comb[8][32][100];  // rows 0..7 used; >80KB forces 1 blk/CU
    __shared__ float bxv[96], bhv[96];

    if (tid < 96) {
        const int g3 = tid >> 5, jj = tid & 31;
        bxv[tid] = bx[g3 * 1024 + j0 + jj];
        bhv[tid] = bh[g3 * 1024 + j0 + jj];
    }
    const int grow = tid >> 4, jp = (tid & 15) * 2;  // gate map (tid<128)
    float hp0 = 0.f, hp1 = 0.f;
    if (tid < 128) {
        const float2 h2 = *(const float2*)(hstate + (size_t)(bg0 + grow) * 1024 + j0 + jp);
        hp0 = h2.x; hp1 = h2.y;
    }

    // ---- h-weight fragments resident in VGPRs (32 cols x own K-slice) ----
    bf16x8 wf[6][4];
#pragma unroll
    for (int nt = 0; nt < 6; ++nt) {
        const int n96 = nt * 16 + lm, g3 = n96 >> 5, jj = n96 & 31;
        const float* rp = Wh + (size_t)(g3 * 1024 + j0 + jj) * 1024 + kb + lk * 8;
#pragma unroll
        for (int ks = 0; ks < 4; ++ks)
            wf[nt][ks] = pack8(*(const float4*)(rp + ks * 32), *(const float4*)(rp + ks * 32 + 4));
    }
    __syncthreads();

    // xp register prefetch, double-buffered
    unsigned xa0 = 0, xa1 = 0, xa2 = 0, xb0 = 0, xb1 = 0, xb2 = 0;
    if (tid < 128) {
        const unsigned short* xr = xp + ((size_t)0 * 64 + bg0 + grow) * 3072 + j0 + jp;
        xa0 = *(const unsigned*)(xr);
        xa1 = *(const unsigned*)(xr + 1024);
        xa2 = *(const unsigned*)(xr + 2048);
    }

    const int row_a = (lm < 8) ? lm : 7;  // M=8: clamp A rows 8..15 (discarded)
    unsigned long long rr0, rr1, rr2, rr3, rr4, rr5, rr6, rr7;
    int useMall = 0;  // sticky per-wave fallback

#define L2LOAD(P)                                                              \
    asm volatile(                                                              \
        "global_load_dwordx2 %[a0], %[ad], off sc0\n\t"                        \
        "global_load_dwordx2 %[a1], %[ad], off offset:8 sc0\n\t"               \
        "global_load_dwordx2 %[a2], %[ad], off offset:64 sc0\n\t"              \
        "global_load_dwordx2 %[a3], %[ad], off offset:72 sc0\n\t"              \
        "global_load_dwordx2 %[a4], %[ad], off offset:128 sc0\n\t"             \
        "global_load_dwordx2 %[a5], %[ad], off offset:136 sc0\n\t"             \
        "global_load_dwordx2 %[a6], %[ad], off offset:192 sc0\n\t"             \
        "global_load_dwordx2 %[a7], %[ad], off offset:200 sc0\n\t"             \
        "s_waitcnt vmcnt(0)"                                                   \
        : [a0] "=&v"(rr0), [a1] "=&v"(rr1), [a2] "=&v"(rr2), [a3] "=&v"(rr3),  \
          [a4] "=&v"(rr4), [a5] "=&v"(rr5), [a6] "=&v"(rr6), [a7] "=&v"(rr7)   \
        : [ad] "v"(P)                                                          \
        : "memory")

#pragma unroll 1
    for (int t = t0; t < tend; ++t) {
        const size_t hoff = (size_t)(t & 1) * 65536 + (size_t)g * 8192
                            + (size_t)row_a * 1024 + kb + lk * 8;
        const unsigned long long TAGM = 0x0000000100000001ull;
        const unsigned long long tagrep =
            (unsigned long long)((unsigned)(t >> 1) & 1u) * TAGM;

        // ---- arrival poll: L2 copy fast path, sticky MALL fallback ----
        if (!useMall) {
            const unsigned short* pl = hl2 + hoff;
            int spins = 0;
            for (;;) {
                L2LOAD(pl);
                const unsigned long long bad =
                    ((rr0 ^ tagrep) | (rr1 ^ tagrep) | (rr2 ^ tagrep) | (rr3 ^ tagrep) |
                     (rr4 ^ tagrep) | (rr5 ^ tagrep) | (rr6 ^ tagrep) | (rr7 ^ tagrep)) & TAGM;
                if (__builtin_expect(__all(bad == 0), 1)) break;
                if (++spins > 256) { useMall = 1; break; }
            }
        }
        if (useMall) {
            const unsigned short* pm = hmall + hoff;
            for (;;) {
                rr0 = ald64(pm);       rr1 = ald64(pm + 4);
                rr2 = ald64(pm + 32);  rr3 = ald64(pm + 36);
                rr4 = ald64(pm + 64);  rr5 = ald64(pm + 68);
                rr6 = ald64(pm + 96);  rr7 = ald64(pm + 100);
                const unsigned long long bad =
                    ((rr0 ^ tagrep) | (rr1 ^ tagrep) | (rr2 ^ tagrep) | (rr3 ^ tagrep) |
                     (rr4 ^ tagrep) | (rr5 ^ tagrep) | (rr6 ^ tagrep) | (rr7 ^ tagrep)) & TAGM;
                if (__builtin_expect(__all(bad == 0), 1)) break;
            }
        }

        // xp(t+1) prefetch into the 'next' registers
        if (tid < 128 && t + 1 < tend) {
            const unsigned short* xr = xp + ((size_t)(t + 1 - t0) * 64 + bg0 + grow) * 3072 + j0 + jp;
            xb0 = *(const unsigned*)(xr);
            xb1 = *(const unsigned*)(xr + 1024);
            xb2 = *(const unsigned*)(xr + 2048);
        }

        // ---- MFMA: D[8 x 96] partial over own K-slice ----
        f32x4 acc[6] = {};
#define KSTEP(KA, KB, KS)                                                       \
        do {                                                                    \
            struct U { unsigned long long a, b; } u{KA, KB};                    \
            const bf16x8 af = __builtin_bit_cast(bf16x8, u);                    \
            _Pragma("unroll")                                                   \
            for (int nt = 0; nt < 6; ++nt)                                      \
                acc[nt] = __builtin_amdgcn_mfma_f32_16x16x32_bf16(              \
                    af, wf[nt][KS], acc[nt], 0, 0, 0);                          \
        } while (0)
        KSTEP(rr0, rr1, 0); KSTEP(rr2, rr3, 1); KSTEP(rr4, rr5, 2); KSTEP(rr6, rr7, 3);
#undef KSTEP

        // C/D: col=lane&15, row=lk*4+i; valid batch rows 0..7 need lk<2
        if (lk < 2) {
#pragma unroll
            for (int nt = 0; nt < 6; ++nt)
#pragma unroll
                for (int i = 0; i < 4; ++i)
                    comb[w][lk * 4 + i][nt * 16 + lm] = acc[nt][i];
        }
        asm volatile("s_waitcnt lgkmcnt(0)\ns_barrier" ::: "memory");

        // ---- gate (128 threads: 8 rows x 16 col-pairs) ----
        if (tid < 128) {
            float s00 = 0, s10 = 0, s20 = 0, s01 = 0, s11 = 0, s21 = 0;
#pragma unroll
            for (int ww = 0; ww < 8; ++ww) {
                s00 += comb[ww][grow][jp];      s01 += comb[ww][grow][jp + 1];
                s10 += comb[ww][grow][32 + jp]; s11 += comb[ww][grow][32 + jp + 1];
                s20 += comb[ww][grow][64 + jp]; s21 += comb[ww][grow][64 + jp + 1];
            }
            const float xr0 = bf2f((unsigned short)xa0) + bxv[jp];
            const float xr1 = bf2f((unsigned short)(xa0 >> 16)) + bxv[jp + 1];
            const float xu0 = bf2f((unsigned short)xa1) + bxv[32 + jp];
            const float xu1 = bf2f((unsigned short)(xa1 >> 16)) + bxv[32 + jp + 1];
            const float xn0 = bf2f((unsigned short)xa2) + bxv[64 + jp];
            const float xn1 = bf2f((unsigned short)(xa2 >> 16)) + bxv[64 + jp + 1];
            const float r0 = 1.0f / (1.0f + __expf(-(xr0 + s00 + bhv[jp])));
            const float r1 = 1.0f / (1.0f + __expf(-(xr1 + s01 + bhv[jp + 1])));
            const float u0 = 1.0f / (1.0f + __expf(-(xu0 + s10 + bhv[32 + jp])));
            const float u1 = 1.0f / (1.0f + __expf(-(xu1 + s11 + bhv[32 + jp + 1])));
            const float z0 = xn0 + r0 * (s20 + bhv[64 + jp]);
            const float z1 = xn1 + r1 * (s21 + bhv[64 + jp + 1]);
            const float e0 = __expf(2.0f * z0), e1 = __expf(2.0f * z1);
            const float n0 = 1.0f - 2.0f / (e0 + 1.0f);
            const float n1 = 1.0f - 2.0f / (e1 + 1.0f);
            const float hy0 = u0 * hp0 + (1.0f - u0) * n0;
            const float hy1 = u1 * hp1 + (1.0f - u1) * n1;
            hp0 = hy0; hp1 = hy1;
            const unsigned tagn = ((unsigned)(t + 1) >> 1) & 1u;
            const unsigned v0 = ((unsigned)(unsigned short)f2bf(hy0) & 0xFFFEu) | tagn;
            const unsigned pk = ((unsigned)(unsigned short)f2bf(hy1) << 16) | v0;
            const size_t soff = (size_t)((t + 1) & 1) * 65536 + (size_t)g * 8192
                                + (size_t)grow * 1024 + j0 + jp;
            // dual publish: L2 copy (plain write-through) + MALL copy (agent)
            *(volatile unsigned*)(hl2 + soff) = pk;
            __hip_atomic_store((unsigned*)(hmall + soff), pk, __ATOMIC_RELAXED,
                               __HIP_MEMORY_SCOPE_AGENT);
            if (t == tend - 1)
                *(float2*)(hstate + (size_t)(bg0 + grow) * 1024 + j0 + jp) = make_float2(hy0, hy1);
            if (t == Tt - 1)
                *(float2*)(hfinal + (size_t)(bg0 + grow) * 1024 + j0 + jp) = make_float2(hy0, hy1);
            xa0 = xb0; xa1 = xb1; xa2 = xb2;
        }
        // raw end barrier: comb anti-dependence only (reads retired by data dep)
        asm volatile("s_barrier" ::: "memory");
    }
#undef L2LOAD
}

// ---------------- round-2 fallback scan (ring+flags, MALL path) ---------------
template <bool RING>
__global__ __launch_bounds__(256, 1)
void gru_scan(const float* __restrict__ x,
              const float* __restrict__ Wx, const float* __restrict__ bx,
              const float* __restrict__ Wh, const float* __restrict__ bh,
              unsigned short* __restrict__ hbuf, float* __restrict__ hfinal,
              unsigned short* __restrict__ ring, unsigned* __restrict__ flags) {
    const int tid = threadIdx.x;
    const int w   = tid >> 6;
    const int l   = tid & 63;
    const int bid = blockIdx.x;
    const int g   = bid & 1;
    const int c   = bid >> 1;
    const int bg0 = g * 32;
    const int j0  = c * 8;

    __shared__ float comb[4][32][24];
    __shared__ float hp[32][8];
    __shared__ float bxv[24], bhv[24];

    hp[tid >> 3][tid & 7] = 0.0f;
    if (tid < 24) {
        const int gate = tid >> 3, jj = tid & 7;
        bxv[tid] = bx[gate * 1024 + j0 + jj];
        bhv[tid] = bh[gate * 1024 + j0 + jj];
    }

    const int lm = l & 15;
    const int lk = l >> 4;
    const int wb = w * 512;
    bf16x8 bfr[2][16];
    {
        const float* Wbase = (w < 2) ? Wx : Wh;
        const int krel = (w < 2) ? wb : (wb - 1024);
#pragma unroll
        for (int nt = 0; nt < 2; ++nt) {
            int row24 = nt * 16 + lm;
            if (row24 > 23) row24 = 23;
            const int gate = row24 >> 3, jj = row24 & 7;
            const float* rp = Wbase + (size_t)(gate * 1024 + j0 + jj) * 1024 + krel + lk * 8;
#pragma unroll
            for (int ks = 0; ks < 16; ++ks) {
                float4 a = *(const float4*)(rp + ks * 32);
                float4 b = *(const float4*)(rp + ks * 32 + 4);
                bfr[nt][ks] = pack8(a, b);
            }
        }
    }
    __syncthreads();

    if (RING) {
        if (tid < 128) {
            const int e = c * 256 + tid * 2;
            const int rl = e >> 10, col = e & 1023;
#pragma unroll
            for (int s = 0; s < 4; ++s) {
                const float2 xv = *(const float2*)(x + ((size_t)(bg0 + rl) * Tt + s) * Dd + col);
                unsigned pk = (unsigned)(unsigned short)f2bf(xv.x)
                            | ((unsigned)(unsigned short)f2bf(xv.y) << 16);
                __hip_atomic_store((unsigned*)(ring + (size_t)s * 65536
                                               + (size_t)(bg0 + rl) * 1024 + col),
                                   pk, __ATOMIC_RELAXED, __HIP_MEMORY_SCOPE_AGENT);
            }
        }
        asm volatile("s_waitcnt vmcnt(0)" ::: "memory");
        __syncthreads();
        if (tid == 0)
            __hip_atomic_store(&flags[g * 128 + c], 1u, __ATOMIC_RELAXED,
                               __HIP_MEMORY_SCOPE_AGENT);
        if (tid < 128) {
            const unsigned* f = flags + g * 128 + tid;
            while (aldu32(f) < 1u) __builtin_amdgcn_s_sleep(1);
        }
        asm volatile("" ::: "memory");
        __syncthreads();
    }

#pragma unroll 1
    for (int t = 0; t < Tt; ++t) {
        const unsigned short* hcur = hbuf + (size_t)(t & 1) * Bb * Hh;

        if (RING && tid < 128) {
            const int sp = t + 4;
            if (sp < Tt) {
                const int e = c * 256 + tid * 2;
                const int rl = e >> 10, col = e & 1023;
                const float2 xv = *(const float2*)(x + ((size_t)(bg0 + rl) * Tt + sp) * Dd + col);
                unsigned pk = (unsigned)(unsigned short)f2bf(xv.x)
                            | ((unsigned)(unsigned short)f2bf(xv.y) << 16);
                __hip_atomic_store((unsigned*)(ring + (size_t)(sp & 7) * 65536
                                               + (size_t)(bg0 + rl) * 1024 + col),
                                   pk, __ATOMIC_RELAXED, __HIP_MEMORY_SCOPE_AGENT);
            }
        }

        if (w >= 2 && t > 0) {
            const unsigned tgt = (unsigned)(t + 1);
            const unsigned* f0 = flags + g * 128 + l;
            const unsigned* f1 = f0 + 64;
            while (aldu32(f0) < tgt || aldu32(f1) < tgt) __builtin_amdgcn_s_sleep(1);
        }
        asm volatile("" ::: "memory");

        f32x4 acc[2][2] = {};
        if (RING || w >= 2) {
            const unsigned short* src;
            int colb;
            if (w < 2) { src = ring + (size_t)(t & 7) * 65536; colb = wb; }
            else       { src = hcur;                           colb = wb - 1024; }
#pragma unroll
            for (int half = 0; half < 2; ++half) {
                unsigned long long stg[8][2][2];
#pragma unroll
                for (int k8 = 0; k8 < 8; ++k8) {
                    const int ks = half * 8 + k8;
#pragma unroll
                    for (int mt = 0; mt < 2; ++mt) {
                        const unsigned short* p = src + (size_t)(bg0 + mt * 16 + lm) * 1024
                                                  + colb + ks * 32 + lk * 8;
                        stg[k8][mt][0] = ald64(p);
                        stg[k8][mt][1] = ald64(p + 4);
                    }
                }
#pragma unroll
                for (int k8 = 0; k8 < 8; ++k8) {
                    const int ks = half * 8 + k8;
#pragma unroll
                    for (int mt = 0; mt < 2; ++mt) {
                        struct { unsigned long long a, b; } u{stg[k8][mt][0], stg[k8][mt][1]};
                        bf16x8 af = __builtin_bit_cast(bf16x8, u);
                        acc[mt][0] = __builtin_amdgcn_mfma_f32_16x16x32_bf16(af, bfr[0][ks], acc[mt][0], 0, 0, 0);
                        acc[mt][1] = __builtin_amdgcn_mfma_f32_16x16x32_bf16(af, bfr[1][ks], acc[mt][1], 0, 0, 0);
                    }
                }
            }
        } else {
#pragma unroll
            for (int ks = 0; ks < 16; ++ks) {
#pragma unroll
                for (int mt = 0; mt < 2; ++mt) {
                    const size_t row = (size_t)(bg0 + mt * 16 + lm);
                    const size_t off = (row * Tt + t) * Dd + wb + ks * 32 + lk * 8;
                    float4 a = *(const float4*)(x + off);
                    float4 b = *(const float4*)(x + off + 4);
                    bf16x8 af = pack8(a, b);
                    acc[mt][0] = __builtin_amdgcn_mfma_f32_16x16x32_bf16(af, bfr[0][ks], acc[mt][0], 0, 0, 0);
                    acc[mt][1] = __builtin_amdgcn_mfma_f32_16x16x32_bf16(af, bfr[1][ks], acc[mt][1], 0, 0, 0);
                }
            }
        }

#pragma unroll
        for (int mt = 0; mt < 2; ++mt)
#pragma unroll
            for (int nt = 0; nt < 2; ++nt) {
                const int n = nt * 16 + lm;
                if (n < 24) {
#pragma unroll
                    for (int i = 0; i < 4; ++i)
                        comb[w][mt * 16 + lk * 4 + i][n] = acc[mt][nt][i];
                }
            }
        __syncthreads();

        {
            const int b = tid >> 3, j = tid & 7;
            const float rz = comb[0][b][j] + comb[1][b][j] + comb[2][b][j] + comb[3][b][j]
                             + bxv[j] + bhv[j];
            const float uz = comb[0][b][8 + j] + comb[1][b][8 + j] + comb[2][b][8 + j]
                             + comb[3][b][8 + j] + bxv[8 + j] + bhv[8 + j];
            const float nx = comb[0][b][16 + j] + comb[1][b][16 + j] + bxv[16 + j];
            const float nh = comb[2][b][16 + j] + comb[3][b][16 + j] + bhv[16 + j];
            const float r  = 1.0f / (1.0f + __expf(-rz));
            const float u  = 1.0f / (1.0f + __expf(-uz));
            const float zz = nx + r * nh;
            const float e2 = __expf(2.0f * zz);
            const float nv = 1.0f - 2.0f / (e2 + 1.0f);
            const float hold = hp[b][j];
            const float hy = u * hold + (1.0f - u) * nv;
            hp[b][j] = hy;
            unsigned short* hn = hbuf + (size_t)((t + 1) & 1) * Bb * Hh
                                 + (size_t)(bg0 + b) * 1024 + j0 + j;
            __hip_atomic_store(hn, (unsigned short)f2bf(hy), __ATOMIC_RELAXED,
                               __HIP_MEMORY_SCOPE_AGENT);
            if (t == Tt - 1) hfinal[(size_t)(bg0 + b) * 1024 + j0 + j] = hy;
        }
        asm volatile("s_waitcnt vmcnt(0)" ::: "memory");
        __syncthreads();
        if (tid == 0 && t + 1 < Tt)
            __hip_atomic_store(&flags[g * 128 + c], (unsigned)(t + 2), __ATOMIC_RELAXED,
                               __HIP_MEMORY_SCOPE_AGENT);
    }
}

// ---------------- final projection + log_softmax ------------------------------
__global__ __launch_bounds__(1024)
void final_kernel(const float* __restrict__ hfinal, const float* __restrict__ Wf,
                  const float* __restrict__ bfv, float* __restrict__ out) {
    const int b = blockIdx.x;
    const int o = threadIdx.x;
    __shared__ float hs[1024];
    __shared__ float redm[16], redsum[16], bcast[2];
    hs[o] = hfinal[(size_t)b * 1024 + o];
    __syncthreads();

    const float* wr = Wf + (size_t)o * 1024;
    float acc = bfv[o];
#pragma unroll 4
    for (int k = 0; k < 1024; k += 4) {
        float4 wv = *(const float4*)(wr + k);
        acc += hs[k] * wv.x + hs[k + 1] * wv.y + hs[k + 2] * wv.z + hs[k + 3] * wv.w;
    }

    float m = acc;
#pragma unroll
    for (int off = 32; off > 0; off >>= 1) m = fmaxf(m, __shfl_xor(m, off));
    if ((o & 63) == 0) redm[o >> 6] = m;
    __syncthreads();
    if (o == 0) {
        float mm = redm[0];
#pragma unroll
        for (int i = 1; i < 16; ++i) mm = fmaxf(mm, redm[i]);
        bcast[0] = mm;
    }
    __syncthreads();
    const float bm = bcast[0];
    float s = __expf(acc - bm);
#pragma unroll
    for (int off = 32; off > 0; off >>= 1) s += __shfl_xor(s, off);
    if ((o & 63) == 0) redsum[o >> 6] = s;
    __syncthreads();
    if (o == 0) {
        float ss = 0.0f;
        for (int i = 0; i < 16; ++i) ss += redsum[i];
        bcast[1] = logf(ss);
    }
    __syncthreads();
    out[(size_t)b * 1024 + o] = acc - bm - bcast[1];
}

// ---------------- launch ------------------------------------------------------
extern "C" void kernel_launch(void* const* d_in, const int* in_sizes, int n_in,
                              void* d_out, int out_size, void* d_ws, size_t ws_size,
                              hipStream_t stream) {
    (void)in_sizes; (void)n_in; (void)out_size;
    const float* x   = (const float*)d_in[0];
    const float* Wx  = (const float*)d_in[1];
    const float* bx  = (const float*)d_in[2];
    const float* Wh  = (const float*)d_in[3];
    const float* bh  = (const float*)d_in[4];
    const float* Wf  = (const float*)d_in[5];
    const float* bfv = (const float*)d_in[6];
    float* out = (float*)d_out;
    char* ws = (char*)d_ws;

    // Path A layout (identical to round 7)
    const size_t HL = 1024;                     // hl2:   2 x 8 x 8 x 1024 bf16 = 256 KB
    const size_t HM = HL + 262144;              // hmall: 256 KB
    const size_t HS = HM + 262144;              // hstate fp32 256 KB
    const size_t HF = HS + 262144;              // hfinal fp32 256 KB
    const size_t WX = HF + 262144;              // Wx bf16 6 MB
    const size_t XP = WX + 6291456;             // xp: W x 64x3072 bf16
    size_t avail = (ws_size > XP) ? (ws_size - XP) : 0;
    long Wl = (long)(avail / 393216);
    if (Wl > 2048) Wl = 2048;
    const int W = (int)Wl;

    if (W >= 32) {
        unsigned short* hl2   = (unsigned short*)(ws + HL);
        unsigned short* hmall = (unsigned short*)(ws + HM);
        float* hstate         = (float*)(ws + HS);
        float* hfinal         = (float*)(ws + HF);
        unsigned short* Wxb   = (unsigned short*)(ws + WX);
        unsigned short* xp    = (unsigned short*)(ws + XP);

        // ring init (both copies): slot 0 = h0 = 0 (tag 0); slot 1 = 0xFF (stale)
        hipMemsetAsync(ws + HL, 0x00, 131072, stream);
        hipMemsetAsync(ws + HL + 131072, 0xFF, 131072, stream);
        hipMemsetAsync(ws + HM, 0x00, 131072, stream);
        hipMemsetAsync(ws + HM + 131072, 0xFF, 131072, stream);
        hipMemsetAsync(ws + HS, 0x00, 262144, stream);
        wcvt<<<1536, 256, 0, stream>>>(Wx, (unsigned short*)Wxb, 3L * 1024 * 1024);
        for (int t0 = 0; t0 < Tt; t0 += W) {
            const int Wc = (Tt - t0 < W) ? (Tt - t0) : W;
            xp_gemm2<<<dim3(24, Wc), 256, 0, stream>>>(x, Wxb, xp, t0);
            gru_scan6<<<256, 512, 0, stream>>>(Wh, bx, bh, hl2, hmall, hstate,
                                               hfinal, xp, t0, t0 + Wc);
        }
        final_kernel<<<64, 1024, 0, stream>>>(hfinal, Wf, bfv, out);
    } else {
        // round-2 fallback layout
        unsigned* flags      = (unsigned*)ws;                                  // 1 KB
        unsigned short* hbuf = (unsigned short*)(ws + 1024);                   // 256 KB
        float* hfinal        = (float*)(ws + 1024 + 262144);                   // 256 KB
        unsigned short* ring = (unsigned short*)(ws + 1024 + 262144 + 262144); // 1 MB
        const size_t need_ring = 1024 + 262144 + 262144 + (size_t)8 * 131072;
        const bool use_ring = (ws_size >= need_ring);

        hipMemsetAsync(d_ws, 0, 1024 + (size_t)Bb * Hh * 2, stream);
        if (use_ring)
            gru_scan<true><<<256, 256, 0, stream>>>(x, Wx, bx, Wh, bh, hbuf, hfinal, ring, flags);
        else
            gru_scan<false><<<256, 256, 0, stream>>>(x, Wx, bx, Wh, bh, hbuf, hfinal, ring, flags);
        final_kernel<<<64, 1024, 0, stream>>>(hfinal, Wf, bfv, out);
    }
}

// Round 13
// 10164.041 us; speedup vs baseline: 1.4629x; 1.4629x over previous
//
#include <hip/hip_runtime.h>
#include <hip/hip_bf16.h>

// GRU: B=64, T=2048, D=H=O=1024.
// Path A: xp = x@Wx^T precomputed (LDS-staged bf16 GEMM, DOUBLE-BUFFERED:
// one barrier per K-step), then h-only persistent scan = EXACT round-7
// structure (best measured: ~8.1 ms):
//   256 blocks x 512 thr (1 blk/CU via LDS>100KB). g=bid&7 -> 8 batch rows,
//   c=bid>>3 -> 32 columns. Dual-publish h: L2 copy (plain store, sc0 batched
//   hammer poll) + MALL copy (agent store, sticky fallback after 256 spins).
//   Tag-in-value sync (LSB parity), 2-slot ring, two barriers per step.
// Fallback (small ws): round-2 ring kernel.

#define Bb 64
#define Tt 2048
#define Dd 1024
#define Hh 1024

typedef __attribute__((ext_vector_type(8))) short bf16x8;
typedef __attribute__((ext_vector_type(4))) float f32x4;

__device__ __forceinline__ short f2bf(float x) {
    __hip_bfloat16 h = __float2bfloat16(x);
    return __builtin_bit_cast(short, h);
}
__device__ __forceinline__ float bf2f(unsigned short u) {
    return __builtin_bit_cast(float, (unsigned)u << 16);
}
__device__ __forceinline__ bf16x8 pack8(float4 a, float4 b) {
    bf16x8 f;
    f[0] = f2bf(a.x); f[1] = f2bf(a.y); f[2] = f2bf(a.z); f[3] = f2bf(a.w);
    f[4] = f2bf(b.x); f[5] = f2bf(b.y); f[6] = f2bf(b.z); f[7] = f2bf(b.w);
    return f;
}
__device__ __forceinline__ unsigned long long ald64(const void* p) {
    return __hip_atomic_load((const unsigned long long*)p, __ATOMIC_RELAXED,
                             __HIP_MEMORY_SCOPE_AGENT);
}
__device__ __forceinline__ unsigned aldu32(const unsigned* p) {
    return __hip_atomic_load(p, __ATOMIC_RELAXED, __HIP_MEMORY_SCOPE_AGENT);
}

// ---------------- fp32 -> bf16 convert (weights) ------------------------------
__global__ void wcvt(const float* __restrict__ a, unsigned short* __restrict__ o, long n) {
    long i = ((long)blockIdx.x * blockDim.x + threadIdx.x) * 8;
    long stride = (long)gridDim.x * blockDim.x * 8;
    for (; i < n; i += stride)
        *(bf16x8*)(o + i) = pack8(*(const float4*)(a + i), *(const float4*)(a + i + 4));
}

// ---------------- xp GEMM v3: LDS-staged, double-buffered ---------------------
// grid (24, Wc). Identical mapping to the verified r7 xp_gemm, but As is
// double-buffered: stage chunk k0+32 into buf^1 while computing from buf;
// ONE barrier per K-step instead of two.
__global__ __launch_bounds__(256)
void xp_gemm3(const float* __restrict__ x, const unsigned short* __restrict__ Wxb,
              unsigned short* __restrict__ xp, int t0) {
    __shared__ unsigned short As[2][64][40];
    const int tid = threadIdx.x;
    const int wave = tid >> 6, l = tid & 63, lm = l & 15, lk = l >> 4;
    const int slot = blockIdx.y;
    const int t = t0 + slot;
    const int n0w = blockIdx.x * 128 + wave * 32;
    const int r = tid >> 2, kq = (tid & 3) * 8;
    const float* xrow = x + (size_t)r * Tt * Dd + (size_t)t * Dd;

    // prologue: stage chunk 0 into buf 0
    {
        const float* p = xrow + kq;
        *(bf16x8*)&As[0][r][kq] = pack8(*(const float4*)p, *(const float4*)(p + 4));
    }
    __syncthreads();

    f32x4 acc[4][2] = {};
#pragma unroll 1
    for (int k0 = 0; k0 < 1024; k0 += 32) {
        const int buf = (k0 >> 5) & 1;
        // stage next chunk into the other buffer (overlaps with MFMAs below)
        if (k0 + 32 < 1024) {
            const float* p = xrow + k0 + 32 + kq;
            *(bf16x8*)&As[buf ^ 1][r][kq] = pack8(*(const float4*)p, *(const float4*)(p + 4));
        }
        bf16x8 bfr[2];
#pragma unroll
        for (int nt = 0; nt < 2; ++nt)
            bfr[nt] = *(const bf16x8*)(Wxb + (size_t)(n0w + nt * 16 + lm) * 1024 + k0 + lk * 8);
#pragma unroll
        for (int mt = 0; mt < 4; ++mt) {
            const bf16x8 af = *(const bf16x8*)&As[buf][mt * 16 + lm][lk * 8];
            acc[mt][0] = __builtin_amdgcn_mfma_f32_16x16x32_bf16(af, bfr[0], acc[mt][0], 0, 0, 0);
            acc[mt][1] = __builtin_amdgcn_mfma_f32_16x16x32_bf16(af, bfr[1], acc[mt][1], 0, 0, 0);
        }
        // single barrier: buf^1 writes complete; buf reads retired
        __syncthreads();
    }
    // D[b = mt*16 + lk*4 + i][n = n0w + nt*16 + lm]  (verified mapping)
#pragma unroll
    for (int mt = 0; mt < 4; ++mt)
#pragma unroll
        for (int nt = 0; nt < 2; ++nt)
#pragma unroll
            for (int i = 0; i < 4; ++i) {
                const int b = mt * 16 + lk * 4 + i;
                const int n = n0w + nt * 16 + lm;
                xp[((size_t)slot * 64 + b) * 3072 + n] = (unsigned short)f2bf(acc[mt][nt][i]);
            }
}

// ---------------- dual-publish h-only persistent scan (EXACT round 7) ---------
// 256 blocks x 512 thr, 1 blk/CU. g=bid&7: batch rows 8g..8g+7;
// c=bid>>3: columns [c*32,c*32+32). Wave w: K-slice [w*128,w*128+128).
// hl2 / hmall: [slot 2][group 8][row 8][col 1024] bf16 each.
__global__ __launch_bounds__(512, 2)
void gru_scan6(const float* __restrict__ Wh, const float* __restrict__ bx,
               const float* __restrict__ bh, unsigned short* __restrict__ hl2,
               unsigned short* __restrict__ hmall,
               float* __restrict__ hstate, float* __restrict__ hfinal,
               const unsigned short* __restrict__ xp, int t0, int tend) {
    const int tid = threadIdx.x;
    const int w = tid >> 6, l = tid & 63, lm = l & 15, lk = l >> 4;
    const int bid = blockIdx.x;
    const int g = bid & 7, c = bid >> 3;
    const int bg0 = g * 8, j0 = c * 32;
    const int kb = w * 128;

    __shared__ float comb[8][32][100];  // rows 0..7 used; >80KB forces 1 blk/CU
    __shared__ float bxv[96], bhv[96];

    if (tid < 96) {
        const int g3 = tid >> 5, jj = tid & 31;
        bxv[tid] = bx[g3 * 1024 + j0 + jj];
        bhv[tid] = bh[g3 * 1024 + j0 + jj];
    }
    const int grow = tid >> 4, jp = (tid & 15) * 2;  // gate map (tid<128)
    float hp0 = 0.f, hp1 = 0.f;
    if (tid < 128) {
        const float2 h2 = *(const float2*)(hstate + (size_t)(bg0 + grow) * 1024 + j0 + jp);
        hp0 = h2.x; hp1 = h2.y;
    }

    // ---- h-weight fragments resident in VGPRs (32 cols x own K-slice) ----
    bf16x8 wf[6][4];
#pragma unroll
    for (int nt = 0; nt < 6; ++nt) {
        const int n96 = nt * 16 + lm, g3 = n96 >> 5, jj = n96 & 31;
        const float* rp = Wh + (size_t)(g3 * 1024 + j0 + jj) * 1024 + kb + lk * 8;
#pragma unroll
        for (int ks = 0; ks < 4; ++ks)
            wf[nt][ks] = pack8(*(const float4*)(rp + ks * 32), *(const float4*)(rp + ks * 32 + 4));
    }
    __syncthreads();

    // xp register prefetch, double-buffered
    unsigned xa0 = 0, xa1 = 0, xa2 = 0, xb0 = 0, xb1 = 0, xb2 = 0;
    if (tid < 128) {
        const unsigned short* xr = xp + ((size_t)0 * 64 + bg0 + grow) * 3072 + j0 + jp;
        xa0 = *(const unsigned*)(xr);
        xa1 = *(const unsigned*)(xr + 1024);
        xa2 = *(const unsigned*)(xr + 2048);
    }

    const int row_a = (lm < 8) ? lm : 7;  // M=8: clamp A rows 8..15 (discarded)
    unsigned long long rr0, rr1, rr2, rr3, rr4, rr5, rr6, rr7;
    int useMall = 0;  // sticky per-wave fallback

#define L2LOAD(P)                                                              \
    asm volatile(                                                              \
        "global_load_dwordx2 %[a0], %[ad], off sc0\n\t"                        \
        "global_load_dwordx2 %[a1], %[ad], off offset:8 sc0\n\t"               \
        "global_load_dwordx2 %[a2], %[ad], off offset:64 sc0\n\t"              \
        "global_load_dwordx2 %[a3], %[ad], off offset:72 sc0\n\t"              \
        "global_load_dwordx2 %[a4], %[ad], off offset:128 sc0\n\t"             \
        "global_load_dwordx2 %[a5], %[ad], off offset:136 sc0\n\t"             \
        "global_load_dwordx2 %[a6], %[ad], off offset:192 sc0\n\t"             \
        "global_load_dwordx2 %[a7], %[ad], off offset:200 sc0\n\t"             \
        "s_waitcnt vmcnt(0)"                                                   \
        : [a0] "=&v"(rr0), [a1] "=&v"(rr1), [a2] "=&v"(rr2), [a3] "=&v"(rr3),  \
          [a4] "=&v"(rr4), [a5] "=&v"(rr5), [a6] "=&v"(rr6), [a7] "=&v"(rr7)   \
        : [ad] "v"(P)                                                          \
        : "memory")

#pragma unroll 1
    for (int t = t0; t < tend; ++t) {
        const size_t hoff = (size_t)(t & 1) * 65536 + (size_t)g * 8192
                            + (size_t)row_a * 1024 + kb + lk * 8;
        const unsigned long long TAGM = 0x0000000100000001ull;
        const unsigned long long tagrep =
            (unsigned long long)((unsigned)(t >> 1) & 1u) * TAGM;

        // ---- arrival poll: L2 copy fast path, sticky MALL fallback ----
        if (!useMall) {
            const unsigned short* pl = hl2 + hoff;
            int spins = 0;
            for (;;) {
                L2LOAD(pl);
                const unsigned long long bad =
                    ((rr0 ^ tagrep) | (rr1 ^ tagrep) | (rr2 ^ tagrep) | (rr3 ^ tagrep) |
                     (rr4 ^ tagrep) | (rr5 ^ tagrep) | (rr6 ^ tagrep) | (rr7 ^ tagrep)) & TAGM;
                if (__builtin_expect(__all(bad == 0), 1)) break;
                if (++spins > 256) { useMall = 1; break; }
            }
        }
        if (useMall) {
            const unsigned short* pm = hmall + hoff;
            for (;;) {
                rr0 = ald64(pm);       rr1 = ald64(pm + 4);
                rr2 = ald64(pm + 32);  rr3 = ald64(pm + 36);
                rr4 = ald64(pm + 64);  rr5 = ald64(pm + 68);
                rr6 = ald64(pm + 96);  rr7 = ald64(pm + 100);
                const unsigned long long bad =
                    ((rr0 ^ tagrep) | (rr1 ^ tagrep) | (rr2 ^ tagrep) | (rr3 ^ tagrep) |
                     (rr4 ^ tagrep) | (rr5 ^ tagrep) | (rr6 ^ tagrep) | (rr7 ^ tagrep)) & TAGM;
                if (__builtin_expect(__all(bad == 0), 1)) break;
            }
        }

        // xp(t+1) prefetch into the 'next' registers
        if (tid < 128 && t + 1 < tend) {
            const unsigned short* xr = xp + ((size_t)(t + 1 - t0) * 64 + bg0 + grow) * 3072 + j0 + jp;
            xb0 = *(const unsigned*)(xr);
            xb1 = *(const unsigned*)(xr + 1024);
            xb2 = *(const unsigned*)(xr + 2048);
        }

        // ---- MFMA: D[8 x 96] partial over own K-slice ----
        f32x4 acc[6] = {};
#define KSTEP(KA, KB, KS)                                                       \
        do {                                                                    \
            struct U { unsigned long long a, b; } u{KA, KB};                    \
            const bf16x8 af = __builtin_bit_cast(bf16x8, u);                    \
            _Pragma("unroll")                                                   \
            for (int nt = 0; nt < 6; ++nt)                                      \
                acc[nt] = __builtin_amdgcn_mfma_f32_16x16x32_bf16(              \
                    af, wf[nt][KS], acc[nt], 0, 0, 0);                          \
        } while (0)
        KSTEP(rr0, rr1, 0); KSTEP(rr2, rr3, 1); KSTEP(rr4, rr5, 2); KSTEP(rr6, rr7, 3);
#undef KSTEP

        // C/D: col=lane&15, row=lk*4+i; valid batch rows 0..7 need lk<2
        if (lk < 2) {
#pragma unroll
            for (int nt = 0; nt < 6; ++nt)
#pragma unroll
                for (int i = 0; i < 4; ++i)
                    comb[w][lk * 4 + i][nt * 16 + lm] = acc[nt][i];
        }
        asm volatile("s_waitcnt lgkmcnt(0)\ns_barrier" ::: "memory");

        // ---- gate (128 threads: 8 rows x 16 col-pairs) ----
        if (tid < 128) {
            float s00 = 0, s10 = 0, s20 = 0, s01 = 0, s11 = 0, s21 = 0;
#pragma unroll
            for (int ww = 0; ww < 8; ++ww) {
                s00 += comb[ww][grow][jp];      s01 += comb[ww][grow][jp + 1];
                s10 += comb[ww][grow][32 + jp]; s11 += comb[ww][grow][32 + jp + 1];
                s20 += comb[ww][grow][64 + jp]; s21 += comb[ww][grow][64 + jp + 1];
            }
            const float xr0 = bf2f((unsigned short)xa0) + bxv[jp];
            const float xr1 = bf2f((unsigned short)(xa0 >> 16)) + bxv[jp + 1];
            const float xu0 = bf2f((unsigned short)xa1) + bxv[32 + jp];
            const float xu1 = bf2f((unsigned short)(xa1 >> 16)) + bxv[32 + jp + 1];
            const float xn0 = bf2f((unsigned short)xa2) + bxv[64 + jp];
            const float xn1 = bf2f((unsigned short)(xa2 >> 16)) + bxv[64 + jp + 1];
            const float r0 = 1.0f / (1.0f + __expf(-(xr0 + s00 + bhv[jp])));
            const float r1 = 1.0f / (1.0f + __expf(-(xr1 + s01 + bhv[jp + 1])));
            const float u0 = 1.0f / (1.0f + __expf(-(xu0 + s10 + bhv[32 + jp])));
            const float u1 = 1.0f / (1.0f + __expf(-(xu1 + s11 + bhv[32 + jp + 1])));
            const float z0 = xn0 + r0 * (s20 + bhv[64 + jp]);
            const float z1 = xn1 + r1 * (s21 + bhv[64 + jp + 1]);
            const float e0 = __expf(2.0f * z0), e1 = __expf(2.0f * z1);
            const float n0 = 1.0f - 2.0f / (e0 + 1.0f);
            const float n1 = 1.0f - 2.0f / (e1 + 1.0f);
            const float hy0 = u0 * hp0 + (1.0f - u0) * n0;
            const float hy1 = u1 * hp1 + (1.0f - u1) * n1;
            hp0 = hy0; hp1 = hy1;
            const unsigned tagn = ((unsigned)(t + 1) >> 1) & 1u;
            const unsigned v0 = ((unsigned)(unsigned short)f2bf(hy0) & 0xFFFEu) | tagn;
            const unsigned pk = ((unsigned)(unsigned short)f2bf(hy1) << 16) | v0;
            const size_t soff = (size_t)((t + 1) & 1) * 65536 + (size_t)g * 8192
                                + (size_t)grow * 1024 + j0 + jp;
            // dual publish: L2 copy (plain write-through) + MALL copy (agent)
            *(volatile unsigned*)(hl2 + soff) = pk;
            __hip_atomic_store((unsigned*)(hmall + soff), pk, __ATOMIC_RELAXED,
                               __HIP_MEMORY_SCOPE_AGENT);
            if (t == tend - 1)
                *(float2*)(hstate + (size_t)(bg0 + grow) * 1024 + j0 + jp) = make_float2(hy0, hy1);
            if (t == Tt - 1)
                *(float2*)(hfinal + (size_t)(bg0 + grow) * 1024 + j0 + jp) = make_float2(hy0, hy1);
            xa0 = xb0; xa1 = xb1; xa2 = xb2;
        }
        // raw end barrier: comb anti-dependence only (reads retired by data dep)
        asm volatile("s_barrier" ::: "memory");
    }
#undef L2LOAD
}

// ---------------- round-2 fallback scan (ring+flags, MALL path) ---------------
template <bool RING>
__global__ __launch_bounds__(256, 1)
void gru_scan(const float* __restrict__ x,
              const float* __restrict__ Wx, const float* __restrict__ bx,
              const float* __restrict__ Wh, const float* __restrict__ bh,
              unsigned short* __restrict__ hbuf, float* __restrict__ hfinal,
              unsigned short* __restrict__ ring, unsigned* __restrict__ flags) {
    const int tid = threadIdx.x;
    const int w   = tid >> 6;
    const int l   = tid & 63;
    const int bid = blockIdx.x;
    const int g   = bid & 1;
    const int c   = bid >> 1;
    const int bg0 = g * 32;
    const int j0  = c * 8;

    __shared__ float comb[4][32][24];
    __shared__ float hp[32][8];
    __shared__ float bxv[24], bhv[24];

    hp[tid >> 3][tid & 7] = 0.0f;
    if (tid < 24) {
        const int gate = tid >> 3, jj = tid & 7;
        bxv[tid] = bx[gate * 1024 + j0 + jj];
        bhv[tid] = bh[gate * 1024 + j0 + jj];
    }

    const int lm = l & 15;
    const int lk = l >> 4;
    const int wb = w * 512;
    bf16x8 bfr[2][16];
    {
        const float* Wbase = (w < 2) ? Wx : Wh;
        const int krel = (w < 2) ? wb : (wb - 1024);
#pragma unroll
        for (int nt = 0; nt < 2; ++nt) {
            int row24 = nt * 16 + lm;
            if (row24 > 23) row24 = 23;
            const int gate = row24 >> 3, jj = row24 & 7;
            const float* rp = Wbase + (size_t)(gate * 1024 + j0 + jj) * 1024 + krel + lk * 8;
#pragma unroll
            for (int ks = 0; ks < 16; ++ks) {
                float4 a = *(const float4*)(rp + ks * 32);
                float4 b = *(const float4*)(rp + ks * 32 + 4);
                bfr[nt][ks] = pack8(a, b);
            }
        }
    }
    __syncthreads();

    if (RING) {
        if (tid < 128) {
            const int e = c * 256 + tid * 2;
            const int rl = e >> 10, col = e & 1023;
#pragma unroll
            for (int s = 0; s < 4; ++s) {
                const float2 xv = *(const float2*)(x + ((size_t)(bg0 + rl) * Tt + s) * Dd + col);
                unsigned pk = (unsigned)(unsigned short)f2bf(xv.x)
                            | ((unsigned)(unsigned short)f2bf(xv.y) << 16);
                __hip_atomic_store((unsigned*)(ring + (size_t)s * 65536
                                               + (size_t)(bg0 + rl) * 1024 + col),
                                   pk, __ATOMIC_RELAXED, __HIP_MEMORY_SCOPE_AGENT);
            }
        }
        asm volatile("s_waitcnt vmcnt(0)" ::: "memory");
        __syncthreads();
        if (tid == 0)
            __hip_atomic_store(&flags[g * 128 + c], 1u, __ATOMIC_RELAXED,
                               __HIP_MEMORY_SCOPE_AGENT);
        if (tid < 128) {
            const unsigned* f = flags + g * 128 + tid;
            while (aldu32(f) < 1u) __builtin_amdgcn_s_sleep(1);
        }
        asm volatile("" ::: "memory");
        __syncthreads();
    }

#pragma unroll 1
    for (int t = 0; t < Tt; ++t) {
        const unsigned short* hcur = hbuf + (size_t)(t & 1) * Bb * Hh;

        if (RING && tid < 128) {
            const int sp = t + 4;
            if (sp < Tt) {
                const int e = c * 256 + tid * 2;
                const int rl = e >> 10, col = e & 1023;
                const float2 xv = *(const float2*)(x + ((size_t)(bg0 + rl) * Tt + sp) * Dd + col);
                unsigned pk = (unsigned)(unsigned short)f2bf(xv.x)
                            | ((unsigned)(unsigned short)f2bf(xv.y) << 16);
                __hip_atomic_store((unsigned*)(ring + (size_t)(sp & 7) * 65536
                                               + (size_t)(bg0 + rl) * 1024 + col),
                                   pk, __ATOMIC_RELAXED, __HIP_MEMORY_SCOPE_AGENT);
            }
        }

        if (w >= 2 && t > 0) {
            const unsigned tgt = (unsigned)(t + 1);
            const unsigned* f0 = flags + g * 128 + l;
            const unsigned* f1 = f0 + 64;
            while (aldu32(f0) < tgt || aldu32(f1) < tgt) __builtin_amdgcn_s_sleep(1);
        }
        asm volatile("" ::: "memory");

        f32x4 acc[2][2] = {};
        if (RING || w >= 2) {
            const unsigned short* src;
            int colb;
            if (w < 2) { src = ring + (size_t)(t & 7) * 65536; colb = wb; }
            else       { src = hcur;                           colb = wb - 1024; }
#pragma unroll
            for (int half = 0; half < 2; ++half) {
                unsigned long long stg[8][2][2];
#pragma unroll
                for (int k8 = 0; k8 < 8; ++k8) {
                    const int ks = half * 8 + k8;
#pragma unroll
                    for (int mt = 0; mt < 2; ++mt) {
                        const unsigned short* p = src + (size_t)(bg0 + mt * 16 + lm) * 1024
                                                  + colb + ks * 32 + lk * 8;
                        stg[k8][mt][0] = ald64(p);
                        stg[k8][mt][1] = ald64(p + 4);
                    }
                }
#pragma unroll
                for (int k8 = 0; k8 < 8; ++k8) {
                    const int ks = half * 8 + k8;
#pragma unroll
                    for (int mt = 0; mt < 2; ++mt) {
                        struct { unsigned long long a, b; } u{stg[k8][mt][0], stg[k8][mt][1]};
                        bf16x8 af = __builtin_bit_cast(bf16x8, u);
                        acc[mt][0] = __builtin_amdgcn_mfma_f32_16x16x32_bf16(af, bfr[0][ks], acc[mt][0], 0, 0, 0);
                        acc[mt][1] = __builtin_amdgcn_mfma_f32_16x16x32_bf16(af, bfr[1][ks], acc[mt][1], 0, 0, 0);
                    }
                }
            }
        } else {
#pragma unroll
            for (int ks = 0; ks < 16; ++ks) {
#pragma unroll
                for (int mt = 0; mt < 2; ++mt) {
                    const size_t row = (size_t)(bg0 + mt * 16 + lm);
                    const size_t off = (row * Tt + t) * Dd + wb + ks * 32 + lk * 8;
                    float4 a = *(const float4*)(x + off);
                    float4 b = *(const float4*)(x + off + 4);
                    bf16x8 af = pack8(a, b);
                    acc[mt][0] = __builtin_amdgcn_mfma_f32_16x16x32_bf16(af, bfr[0][ks], acc[mt][0], 0, 0, 0);
                    acc[mt][1] = __builtin_amdgcn_mfma_f32_16x16x32_bf16(af, bfr[1][ks], acc[mt][1], 0, 0, 0);
                }
            }
        }

#pragma unroll
        for (int mt = 0; mt < 2; ++mt)
#pragma unroll
            for (int nt = 0; nt < 2; ++nt) {
                const int n = nt * 16 + lm;
                if (n < 24) {
#pragma unroll
                    for (int i = 0; i < 4; ++i)
                        comb[w][mt * 16 + lk * 4 + i][n] = acc[mt][nt][i];
                }
            }
        __syncthreads();

        {
            const int b = tid >> 3, j = tid & 7;
            const float rz = comb[0][b][j] + comb[1][b][j] + comb[2][b][j] + comb[3][b][j]
                             + bxv[j] + bhv[j];
            const float uz = comb[0][b][8 + j] + comb[1][b][8 + j] + comb[2][b][8 + j]
                             + comb[3][b][8 + j] + bxv[8 + j] + bhv[8 + j];
            const float nx = comb[0][b][16 + j] + comb[1][b][16 + j] + bxv[16 + j];
            const float nh = comb[2][b][16 + j] + comb[3][b][16 + j] + bhv[16 + j];
            const float r  = 1.0f / (1.0f + __expf(-rz));
            const float u  = 1.0f / (1.0f + __expf(-uz));
            const float zz = nx + r * nh;
            const float e2 = __expf(2.0f * zz);
            const float nv = 1.0f - 2.0f / (e2 + 1.0f);
            const float hold = hp[b][j];
            const float hy = u * hold + (1.0f - u) * nv;
            hp[b][j] = hy;
            unsigned short* hn = hbuf + (size_t)((t + 1) & 1) * Bb * Hh
                                 + (size_t)(bg0 + b) * 1024 + j0 + j;
            __hip_atomic_store(hn, (unsigned short)f2bf(hy), __ATOMIC_RELAXED,
                               __HIP_MEMORY_SCOPE_AGENT);
            if (t == Tt - 1) hfinal[(size_t)(bg0 + b) * 1024 + j0 + j] = hy;
        }
        asm volatile("s_waitcnt vmcnt(0)" ::: "memory");
        __syncthreads();
        if (tid == 0 && t + 1 < Tt)
            __hip_atomic_store(&flags[g * 128 + c], (unsigned)(t + 2), __ATOMIC_RELAXED,
                               __HIP_MEMORY_SCOPE_AGENT);
    }
}

// ---------------- final projection + log_softmax ------------------------------
__global__ __launch_bounds__(1024)
void final_kernel(const float* __restrict__ hfinal, const float* __restrict__ Wf,
                  const float* __restrict__ bfv, float* __restrict__ out) {
    const int b = blockIdx.x;
    const int o = threadIdx.x;
    __shared__ float hs[1024];
    __shared__ float redm[16], redsum[16], bcast[2];
    hs[o] = hfinal[(size_t)b * 1024 + o];
    __syncthreads();

    const float* wr = Wf + (size_t)o * 1024;
    float acc = bfv[o];
#pragma unroll 4
    for (int k = 0; k < 1024; k += 4) {
        float4 wv = *(const float4*)(wr + k);
        acc += hs[k] * wv.x + hs[k + 1] * wv.y + hs[k + 2] * wv.z + hs[k + 3] * wv.w;
    }

    float m = acc;
#pragma unroll
    for (int off = 32; off > 0; off >>= 1) m = fmaxf(m, __shfl_xor(m, off));
    if ((o & 63) == 0) redm[o >> 6] = m;
    __syncthreads();
    if (o == 0) {
        float mm = redm[0];
#pragma unroll
        for (int i = 1; i < 16; ++i) mm = fmaxf(mm, redm[i]);
        bcast[0] = mm;
    }
    __syncthreads();
    const float bm = bcast[0];
    float s = __expf(acc - bm);
#pragma unroll
    for (int off = 32; off > 0; off >>= 1) s += __shfl_xor(s, off);
    if ((o & 63) == 0) redsum[o >> 6] = s;
    __syncthreads();
    if (o == 0) {
        float ss = 0.0f;
        for (int i = 0; i < 16; ++i) ss += redsum[i];
        bcast[1] = logf(ss);
    }
    __syncthreads();
    out[(size_t)b * 1024 + o] = acc - bm - bcast[1];
}

// ---------------- launch ------------------------------------------------------
extern "C" void kernel_launch(void* const* d_in, const int* in_sizes, int n_in,
                              void* d_out, int out_size, void* d_ws, size_t ws_size,
                              hipStream_t stream) {
    (void)in_sizes; (void)n_in; (void)out_size;
    const float* x   = (const float*)d_in[0];
    const float* Wx  = (const float*)d_in[1];
    const float* bx  = (const float*)d_in[2];
    const float* Wh  = (const float*)d_in[3];
    const float* bh  = (const float*)d_in[4];
    const float* Wf  = (const float*)d_in[5];
    const float* bfv = (const float*)d_in[6];
    float* out = (float*)d_out;
    char* ws = (char*)d_ws;

    // Path A layout (identical to round 7)
    const size_t HL = 1024;                     // hl2:   2 x 8 x 8 x 1024 bf16 = 256 KB
    const size_t HM = HL + 262144;              // hmall: 256 KB
    const size_t HS = HM + 262144;              // hstate fp32 256 KB
    const size_t HF = HS + 262144;              // hfinal fp32 256 KB
    const size_t WX = HF + 262144;              // Wx bf16 6 MB
    const size_t XP = WX + 6291456;             // xp: W x 64x3072 bf16
    size_t avail = (ws_size > XP) ? (ws_size - XP) : 0;
    long Wl = (long)(avail / 393216);
    if (Wl > 2048) Wl = 2048;
    const int W = (int)Wl;

    if (W >= 32) {
        unsigned short* hl2   = (unsigned short*)(ws + HL);
        unsigned short* hmall = (unsigned short*)(ws + HM);
        float* hstate         = (float*)(ws + HS);
        float* hfinal         = (float*)(ws + HF);
        unsigned short* Wxb   = (unsigned short*)(ws + WX);
        unsigned short* xp    = (unsigned short*)(ws + XP);

        // ring init (both copies): slot 0 = h0 = 0 (tag 0); slot 1 = 0xFF (stale)
        hipMemsetAsync(ws + HL, 0x00, 131072, stream);
        hipMemsetAsync(ws + HL + 131072, 0xFF, 131072, stream);
        hipMemsetAsync(ws + HM, 0x00, 131072, stream);
        hipMemsetAsync(ws + HM + 131072, 0xFF, 131072, stream);
        hipMemsetAsync(ws + HS, 0x00, 262144, stream);
        wcvt<<<1536, 256, 0, stream>>>(Wx, (unsigned short*)Wxb, 3L * 1024 * 1024);
        for (int t0 = 0; t0 < Tt; t0 += W) {
            const int Wc = (Tt - t0 < W) ? (Tt - t0) : W;
            xp_gemm3<<<dim3(24, Wc), 256, 0, stream>>>(x, Wxb, xp, t0);
            gru_scan6<<<256, 512, 0, stream>>>(Wh, bx, bh, hl2, hmall, hstate,
                                               hfinal, xp, t0, t0 + Wc);
        }
        final_kernel<<<64, 1024, 0, stream>>>(hfinal, Wf, bfv, out);
    } else {
        // round-2 fallback layout
        unsigned* flags      = (unsigned*)ws;                                  // 1 KB
        unsigned short* hbuf = (unsigned short*)(ws + 1024);                   // 256 KB
        float* hfinal        = (float*)(ws + 1024 + 262144);                   // 256 KB
        unsigned short* ring = (unsigned short*)(ws + 1024 + 262144 + 262144); // 1 MB
        const size_t need_ring = 1024 + 262144 + 262144 + (size_t)8 * 131072;
        const bool use_ring = (ws_size >= need_ring);

        hipMemsetAsync(d_ws, 0, 1024 + (size_t)Bb * Hh * 2, stream);
        if (use_ring)
            gru_scan<true><<<256, 256, 0, stream>>>(x, Wx, bx, Wh, bh, hbuf, hfinal, ring, flags);
        else
            gru_scan<false><<<256, 256, 0, stream>>>(x, Wx, bx, Wh, bh, hbuf, hfinal, ring, flags);
        final_kernel<<<64, 1024, 0, stream>>>(hfinal, Wf, bfv, out);
    }
}

// Round 14
// 9983.152 us; speedup vs baseline: 1.4894x; 1.0181x over previous
//
#include <hip/hip_runtime.h>
#include <hip/hip_bf16.h>

// GRU: B=64, T=2048, D=H=O=1024.
// Path A+: x pre-converted to bf16 (xb, MALL-resident) once; xp = xb@Wxb^T
// via LDS-staged double-buffered bf16 GEMM (xp_gemm4); then h-only persistent
// scan = EXACT round-7 structure (best measured ~8.2 ms):
//   256 blocks x 512 thr (1 blk/CU via LDS>100KB). g=bid&7 (8 batch rows),
//   c=bid>>3 (32 cols). Dual-publish h: L2 copy (plain store, sc0 batched
//   hammer poll) + MALL copy (agent store, sticky fallback). Tag-in-value
//   sync (LSB parity), 2-slot ring, two barriers per step.
// ws-gated: no room for xb -> r13 fp32 xp_gemm3; tiny ws -> round-2 kernel.

#define Bb 64
#define Tt 2048
#define Dd 1024
#define Hh 1024

typedef __attribute__((ext_vector_type(8))) short bf16x8;
typedef __attribute__((ext_vector_type(4))) float f32x4;

__device__ __forceinline__ short f2bf(float x) {
    __hip_bfloat16 h = __float2bfloat16(x);
    return __builtin_bit_cast(short, h);
}
__device__ __forceinline__ float bf2f(unsigned short u) {
    return __builtin_bit_cast(float, (unsigned)u << 16);
}
__device__ __forceinline__ bf16x8 pack8(float4 a, float4 b) {
    bf16x8 f;
    f[0] = f2bf(a.x); f[1] = f2bf(a.y); f[2] = f2bf(a.z); f[3] = f2bf(a.w);
    f[4] = f2bf(b.x); f[5] = f2bf(b.y); f[6] = f2bf(b.z); f[7] = f2bf(b.w);
    return f;
}
__device__ __forceinline__ unsigned long long ald64(const void* p) {
    return __hip_atomic_load((const unsigned long long*)p, __ATOMIC_RELAXED,
                             __HIP_MEMORY_SCOPE_AGENT);
}
__device__ __forceinline__ unsigned aldu32(const unsigned* p) {
    return __hip_atomic_load(p, __ATOMIC_RELAXED, __HIP_MEMORY_SCOPE_AGENT);
}

// ---------------- fp32 -> bf16 convert (weights / x) --------------------------
__global__ void wcvt(const float* __restrict__ a, unsigned short* __restrict__ o, long n) {
    long i = ((long)blockIdx.x * blockDim.x + threadIdx.x) * 8;
    long stride = (long)gridDim.x * blockDim.x * 8;
    for (; i < n; i += stride)
        *(bf16x8*)(o + i) = pack8(*(const float4*)(a + i), *(const float4*)(a + i + 4));
}

// ---------------- xp GEMM v4: bf16 source, LDS-staged, double-buffered --------
// grid (24, Wc). Same mapping/output layout as verified r7 xp_gemm.
__global__ __launch_bounds__(256)
void xp_gemm4(const unsigned short* __restrict__ xb, const unsigned short* __restrict__ Wxb,
              unsigned short* __restrict__ xp, int t0) {
    __shared__ unsigned short As[2][64][40];
    const int tid = threadIdx.x;
    const int wave = tid >> 6, l = tid & 63, lm = l & 15, lk = l >> 4;
    const int slot = blockIdx.y;
    const int t = t0 + slot;
    const int n0w = blockIdx.x * 128 + wave * 32;
    const int r = tid >> 2, kq = (tid & 3) * 8;
    const unsigned short* xrow = xb + (size_t)r * Tt * Dd + (size_t)t * Dd;

    // prologue: stage chunk 0 into buf 0 (16B/lane, no packing)
    *(bf16x8*)&As[0][r][kq] = *(const bf16x8*)(xrow + kq);
    __syncthreads();

    f32x4 acc[4][2] = {};
#pragma unroll 1
    for (int k0 = 0; k0 < 1024; k0 += 32) {
        const int buf = (k0 >> 5) & 1;
        if (k0 + 32 < 1024)
            *(bf16x8*)&As[buf ^ 1][r][kq] = *(const bf16x8*)(xrow + k0 + 32 + kq);
        bf16x8 bfr[2];
#pragma unroll
        for (int nt = 0; nt < 2; ++nt)
            bfr[nt] = *(const bf16x8*)(Wxb + (size_t)(n0w + nt * 16 + lm) * 1024 + k0 + lk * 8);
#pragma unroll
        for (int mt = 0; mt < 4; ++mt) {
            const bf16x8 af = *(const bf16x8*)&As[buf][mt * 16 + lm][lk * 8];
            acc[mt][0] = __builtin_amdgcn_mfma_f32_16x16x32_bf16(af, bfr[0], acc[mt][0], 0, 0, 0);
            acc[mt][1] = __builtin_amdgcn_mfma_f32_16x16x32_bf16(af, bfr[1], acc[mt][1], 0, 0, 0);
        }
        __syncthreads();
    }
#pragma unroll
    for (int mt = 0; mt < 4; ++mt)
#pragma unroll
        for (int nt = 0; nt < 2; ++nt)
#pragma unroll
            for (int i = 0; i < 4; ++i) {
                const int b = mt * 16 + lk * 4 + i;
                const int n = n0w + nt * 16 + lm;
                xp[((size_t)slot * 64 + b) * 3072 + n] = (unsigned short)f2bf(acc[mt][nt][i]);
            }
}

// ---------------- xp GEMM v3 (fp32 source; r13 fallback) ----------------------
__global__ __launch_bounds__(256)
void xp_gemm3(const float* __restrict__ x, const unsigned short* __restrict__ Wxb,
              unsigned short* __restrict__ xp, int t0) {
    __shared__ unsigned short As[2][64][40];
    const int tid = threadIdx.x;
    const int wave = tid >> 6, l = tid & 63, lm = l & 15, lk = l >> 4;
    const int slot = blockIdx.y;
    const int t = t0 + slot;
    const int n0w = blockIdx.x * 128 + wave * 32;
    const int r = tid >> 2, kq = (tid & 3) * 8;
    const float* xrow = x + (size_t)r * Tt * Dd + (size_t)t * Dd;

    {
        const float* p = xrow + kq;
        *(bf16x8*)&As[0][r][kq] = pack8(*(const float4*)p, *(const float4*)(p + 4));
    }
    __syncthreads();

    f32x4 acc[4][2] = {};
#pragma unroll 1
    for (int k0 = 0; k0 < 1024; k0 += 32) {
        const int buf = (k0 >> 5) & 1;
        if (k0 + 32 < 1024) {
            const float* p = xrow + k0 + 32 + kq;
            *(bf16x8*)&As[buf ^ 1][r][kq] = pack8(*(const float4*)p, *(const float4*)(p + 4));
        }
        bf16x8 bfr[2];
#pragma unroll
        for (int nt = 0; nt < 2; ++nt)
            bfr[nt] = *(const bf16x8*)(Wxb + (size_t)(n0w + nt * 16 + lm) * 1024 + k0 + lk * 8);
#pragma unroll
        for (int mt = 0; mt < 4; ++mt) {
            const bf16x8 af = *(const bf16x8*)&As[buf][mt * 16 + lm][lk * 8];
            acc[mt][0] = __builtin_amdgcn_mfma_f32_16x16x32_bf16(af, bfr[0], acc[mt][0], 0, 0, 0);
            acc[mt][1] = __builtin_amdgcn_mfma_f32_16x16x32_bf16(af, bfr[1], acc[mt][1], 0, 0, 0);
        }
        __syncthreads();
    }
#pragma unroll
    for (int mt = 0; mt < 4; ++mt)
#pragma unroll
        for (int nt = 0; nt < 2; ++nt)
#pragma unroll
            for (int i = 0; i < 4; ++i) {
                const int b = mt * 16 + lk * 4 + i;
                const int n = n0w + nt * 16 + lm;
                xp[((size_t)slot * 64 + b) * 3072 + n] = (unsigned short)f2bf(acc[mt][nt][i]);
            }
}

// ---------------- dual-publish h-only persistent scan (EXACT round 7) ---------
__global__ __launch_bounds__(512, 2)
void gru_scan6(const float* __restrict__ Wh, const float* __restrict__ bx,
               const float* __restrict__ bh, unsigned short* __restrict__ hl2,
               unsigned short* __restrict__ hmall,
               float* __restrict__ hstate, float* __restrict__ hfinal,
               const unsigned short* __restrict__ xp, int t0, int tend) {
    const int tid = threadIdx.x;
    const int w = tid >> 6, l = tid & 63, lm = l & 15, lk = l >> 4;
    const int bid = blockIdx.x;
    const int g = bid & 7, c = bid >> 3;
    const int bg0 = g * 8, j0 = c * 32;
    const int kb = w * 128;

    __shared__ float comb[8][32][100];  // rows 0..7 used; >80KB forces 1 blk/CU
    __shared__ float bxv[96], bhv[96];

    if (tid < 96) {
        const int g3 = tid >> 5, jj = tid & 31;
        bxv[tid] = bx[g3 * 1024 + j0 + jj];
        bhv[tid] = bh[g3 * 1024 + j0 + jj];
    }
    const int grow = tid >> 4, jp = (tid & 15) * 2;  // gate map (tid<128)
    float hp0 = 0.f, hp1 = 0.f;
    if (tid < 128) {
        const float2 h2 = *(const float2*)(hstate + (size_t)(bg0 + grow) * 1024 + j0 + jp);
        hp0 = h2.x; hp1 = h2.y;
    }

    // ---- h-weight fragments resident in VGPRs (32 cols x own K-slice) ----
    bf16x8 wf[6][4];
#pragma unroll
    for (int nt = 0; nt < 6; ++nt) {
        const int n96 = nt * 16 + lm, g3 = n96 >> 5, jj = n96 & 31;
        const float* rp = Wh + (size_t)(g3 * 1024 + j0 + jj) * 1024 + kb + lk * 8;
#pragma unroll
        for (int ks = 0; ks < 4; ++ks)
            wf[nt][ks] = pack8(*(const float4*)(rp + ks * 32), *(const float4*)(rp + ks * 32 + 4));
    }
    __syncthreads();

    // xp register prefetch, double-buffered
    unsigned xa0 = 0, xa1 = 0, xa2 = 0, xb0 = 0, xb1 = 0, xb2 = 0;
    if (tid < 128) {
        const unsigned short* xr = xp + ((size_t)0 * 64 + bg0 + grow) * 3072 + j0 + jp;
        xa0 = *(const unsigned*)(xr);
        xa1 = *(const unsigned*)(xr + 1024);
        xa2 = *(const unsigned*)(xr + 2048);
    }

    const int row_a = (lm < 8) ? lm : 7;  // M=8: clamp A rows 8..15 (discarded)
    unsigned long long rr0, rr1, rr2, rr3, rr4, rr5, rr6, rr7;
    int useMall = 0;  // sticky per-wave fallback

#define L2LOAD(P)                                                              \
    asm volatile(                                                              \
        "global_load_dwordx2 %[a0], %[ad], off sc0\n\t"                        \
        "global_load_dwordx2 %[a1], %[ad], off offset:8 sc0\n\t"               \
        "global_load_dwordx2 %[a2], %[ad], off offset:64 sc0\n\t"              \
        "global_load_dwordx2 %[a3], %[ad], off offset:72 sc0\n\t"              \
        "global_load_dwordx2 %[a4], %[ad], off offset:128 sc0\n\t"             \
        "global_load_dwordx2 %[a5], %[ad], off offset:136 sc0\n\t"             \
        "global_load_dwordx2 %[a6], %[ad], off offset:192 sc0\n\t"             \
        "global_load_dwordx2 %[a7], %[ad], off offset:200 sc0\n\t"             \
        "s_waitcnt vmcnt(0)"                                                   \
        : [a0] "=&v"(rr0), [a1] "=&v"(rr1), [a2] "=&v"(rr2), [a3] "=&v"(rr3),  \
          [a4] "=&v"(rr4), [a5] "=&v"(rr5), [a6] "=&v"(rr6), [a7] "=&v"(rr7)   \
        : [ad] "v"(P)                                                          \
        : "memory")

#pragma unroll 1
    for (int t = t0; t < tend; ++t) {
        const size_t hoff = (size_t)(t & 1) * 65536 + (size_t)g * 8192
                            + (size_t)row_a * 1024 + kb + lk * 8;
        const unsigned long long TAGM = 0x0000000100000001ull;
        const unsigned long long tagrep =
            (unsigned long long)((unsigned)(t >> 1) & 1u) * TAGM;

        // ---- arrival poll: L2 copy fast path, sticky MALL fallback ----
        if (!useMall) {
            const unsigned short* pl = hl2 + hoff;
            int spins = 0;
            for (;;) {
                L2LOAD(pl);
                const unsigned long long bad =
                    ((rr0 ^ tagrep) | (rr1 ^ tagrep) | (rr2 ^ tagrep) | (rr3 ^ tagrep) |
                     (rr4 ^ tagrep) | (rr5 ^ tagrep) | (rr6 ^ tagrep) | (rr7 ^ tagrep)) & TAGM;
                if (__builtin_expect(__all(bad == 0), 1)) break;
                if (++spins > 256) { useMall = 1; break; }
            }
        }
        if (useMall) {
            const unsigned short* pm = hmall + hoff;
            for (;;) {
                rr0 = ald64(pm);       rr1 = ald64(pm + 4);
                rr2 = ald64(pm + 32);  rr3 = ald64(pm + 36);
                rr4 = ald64(pm + 64);  rr5 = ald64(pm + 68);
                rr6 = ald64(pm + 96);  rr7 = ald64(pm + 100);
                const unsigned long long bad =
                    ((rr0 ^ tagrep) | (rr1 ^ tagrep) | (rr2 ^ tagrep) | (rr3 ^ tagrep) |
                     (rr4 ^ tagrep) | (rr5 ^ tagrep) | (rr6 ^ tagrep) | (rr7 ^ tagrep)) & TAGM;
                if (__builtin_expect(__all(bad == 0), 1)) break;
            }
        }

        // xp(t+1) prefetch into the 'next' registers
        if (tid < 128 && t + 1 < tend) {
            const unsigned short* xr = xp + ((size_t)(t + 1 - t0) * 64 + bg0 + grow) * 3072 + j0 + jp;
            xb0 = *(const unsigned*)(xr);
            xb1 = *(const unsigned*)(xr + 1024);
            xb2 = *(const unsigned*)(xr + 2048);
        }

        // ---- MFMA: D[8 x 96] partial over own K-slice ----
        f32x4 acc[6] = {};
#define KSTEP(KA, KB, KS)                                                       \
        do {                                                                    \
            struct U { unsigned long long a, b; } u{KA, KB};                    \
            const bf16x8 af = __builtin_bit_cast(bf16x8, u);                    \
            _Pragma("unroll")                                                   \
            for (int nt = 0; nt < 6; ++nt)                                      \
                acc[nt] = __builtin_amdgcn_mfma_f32_16x16x32_bf16(              \
                    af, wf[nt][KS], acc[nt], 0, 0, 0);                          \
        } while (0)
        KSTEP(rr0, rr1, 0); KSTEP(rr2, rr3, 1); KSTEP(rr4, rr5, 2); KSTEP(rr6, rr7, 3);
#undef KSTEP

        // C/D: col=lane&15, row=lk*4+i; valid batch rows 0..7 need lk<2
        if (lk < 2) {
#pragma unroll
            for (int nt = 0; nt < 6; ++nt)
#pragma unroll
                for (int i = 0; i < 4; ++i)
                    comb[w][lk * 4 + i][nt * 16 + lm] = acc[nt][i];
        }
        asm volatile("s_waitcnt lgkmcnt(0)\ns_barrier" ::: "memory");

        // ---- gate (128 threads: 8 rows x 16 col-pairs) ----
        if (tid < 128) {
            float s00 = 0, s10 = 0, s20 = 0, s01 = 0, s11 = 0, s21 = 0;
#pragma unroll
            for (int ww = 0; ww < 8; ++ww) {
                s00 += comb[ww][grow][jp];      s01 += comb[ww][grow][jp + 1];
                s10 += comb[ww][grow][32 + jp]; s11 += comb[ww][grow][32 + jp + 1];
                s20 += comb[ww][grow][64 + jp]; s21 += comb[ww][grow][64 + jp + 1];
            }
            const float xr0 = bf2f((unsigned short)xa0) + bxv[jp];
            const float xr1 = bf2f((unsigned short)(xa0 >> 16)) + bxv[jp + 1];
            const float xu0 = bf2f((unsigned short)xa1) + bxv[32 + jp];
            const float xu1 = bf2f((unsigned short)(xa1 >> 16)) + bxv[32 + jp + 1];
            const float xn0 = bf2f((unsigned short)xa2) + bxv[64 + jp];
            const float xn1 = bf2f((unsigned short)(xa2 >> 16)) + bxv[64 + jp + 1];
            const float r0 = 1.0f / (1.0f + __expf(-(xr0 + s00 + bhv[jp])));
            const float r1 = 1.0f / (1.0f + __expf(-(xr1 + s01 + bhv[jp + 1])));
            const float u0 = 1.0f / (1.0f + __expf(-(xu0 + s10 + bhv[32 + jp])));
            const float u1 = 1.0f / (1.0f + __expf(-(xu1 + s11 + bhv[32 + jp + 1])));
            const float z0 = xn0 + r0 * (s20 + bhv[64 + jp]);
            const float z1 = xn1 + r1 * (s21 + bhv[64 + jp + 1]);
            const float e0 = __expf(2.0f * z0), e1 = __expf(2.0f * z1);
            const float n0 = 1.0f - 2.0f / (e0 + 1.0f);
            const float n1 = 1.0f - 2.0f / (e1 + 1.0f);
            const float hy0 = u0 * hp0 + (1.0f - u0) * n0;
            const float hy1 = u1 * hp1 + (1.0f - u1) * n1;
            hp0 = hy0; hp1 = hy1;
            const unsigned tagn = ((unsigned)(t + 1) >> 1) & 1u;
            const unsigned v0 = ((unsigned)(unsigned short)f2bf(hy0) & 0xFFFEu) | tagn;
            const unsigned pk = ((unsigned)(unsigned short)f2bf(hy1) << 16) | v0;
            const size_t soff = (size_t)((t + 1) & 1) * 65536 + (size_t)g * 8192
                                + (size_t)grow * 1024 + j0 + jp;
            // dual publish: L2 copy (plain write-through) + MALL copy (agent)
            *(volatile unsigned*)(hl2 + soff) = pk;
            __hip_atomic_store((unsigned*)(hmall + soff), pk, __ATOMIC_RELAXED,
                               __HIP_MEMORY_SCOPE_AGENT);
            if (t == tend - 1)
                *(float2*)(hstate + (size_t)(bg0 + grow) * 1024 + j0 + jp) = make_float2(hy0, hy1);
            if (t == Tt - 1)
                *(float2*)(hfinal + (size_t)(bg0 + grow) * 1024 + j0 + jp) = make_float2(hy0, hy1);
            xa0 = xb0; xa1 = xb1; xa2 = xb2;
        }
        // raw end barrier: comb anti-dependence only (reads retired by data dep)
        asm volatile("s_barrier" ::: "memory");
    }
#undef L2LOAD
}

// ---------------- round-2 fallback scan (ring+flags, MALL path) ---------------
template <bool RING>
__global__ __launch_bounds__(256, 1)
void gru_scan(const float* __restrict__ x,
              const float* __restrict__ Wx, const float* __restrict__ bx,
              const float* __restrict__ Wh, const float* __restrict__ bh,
              unsigned short* __restrict__ hbuf, float* __restrict__ hfinal,
              unsigned short* __restrict__ ring, unsigned* __restrict__ flags) {
    const int tid = threadIdx.x;
    const int w   = tid >> 6;
    const int l   = tid & 63;
    const int bid = blockIdx.x;
    const int g   = bid & 1;
    const int c   = bid >> 1;
    const int bg0 = g * 32;
    const int j0  = c * 8;

    __shared__ float comb[4][32][24];
    __shared__ float hp[32][8];
    __shared__ float bxv[24], bhv[24];

    hp[tid >> 3][tid & 7] = 0.0f;
    if (tid < 24) {
        const int gate = tid >> 3, jj = tid & 7;
        bxv[tid] = bx[gate * 1024 + j0 + jj];
        bhv[tid] = bh[gate * 1024 + j0 + jj];
    }

    const int lm = l & 15;
    const int lk = l >> 4;
    const int wb = w * 512;
    bf16x8 bfr[2][16];
    {
        const float* Wbase = (w < 2) ? Wx : Wh;
        const int krel = (w < 2) ? wb : (wb - 1024);
#pragma unroll
        for (int nt = 0; nt < 2; ++nt) {
            int row24 = nt * 16 + lm;
            if (row24 > 23) row24 = 23;
            const int gate = row24 >> 3, jj = row24 & 7;
            const float* rp = Wbase + (size_t)(gate * 1024 + j0 + jj) * 1024 + krel + lk * 8;
#pragma unroll
            for (int ks = 0; ks < 16; ++ks) {
                float4 a = *(const float4*)(rp + ks * 32);
                float4 b = *(const float4*)(rp + ks * 32 + 4);
                bfr[nt][ks] = pack8(a, b);
            }
        }
    }
    __syncthreads();

    if (RING) {
        if (tid < 128) {
            const int e = c * 256 + tid * 2;
            const int rl = e >> 10, col = e & 1023;
#pragma unroll
            for (int s = 0; s < 4; ++s) {
                const float2 xv = *(const float2*)(x + ((size_t)(bg0 + rl) * Tt + s) * Dd + col);
                unsigned pk = (unsigned)(unsigned short)f2bf(xv.x)
                            | ((unsigned)(unsigned short)f2bf(xv.y) << 16);
                __hip_atomic_store((unsigned*)(ring + (size_t)s * 65536
                                               + (size_t)(bg0 + rl) * 1024 + col),
                                   pk, __ATOMIC_RELAXED, __HIP_MEMORY_SCOPE_AGENT);
            }
        }
        asm volatile("s_waitcnt vmcnt(0)" ::: "memory");
        __syncthreads();
        if (tid == 0)
            __hip_atomic_store(&flags[g * 128 + c], 1u, __ATOMIC_RELAXED,
                               __HIP_MEMORY_SCOPE_AGENT);
        if (tid < 128) {
            const unsigned* f = flags + g * 128 + tid;
            while (aldu32(f) < 1u) __builtin_amdgcn_s_sleep(1);
        }
        asm volatile("" ::: "memory");
        __syncthreads();
    }

#pragma unroll 1
    for (int t = 0; t < Tt; ++t) {
        const unsigned short* hcur = hbuf + (size_t)(t & 1) * Bb * Hh;

        if (RING && tid < 128) {
            const int sp = t + 4;
            if (sp < Tt) {
                const int e = c * 256 + tid * 2;
                const int rl = e >> 10, col = e & 1023;
                const float2 xv = *(const float2*)(x + ((size_t)(bg0 + rl) * Tt + sp) * Dd + col);
                unsigned pk = (unsigned)(unsigned short)f2bf(xv.x)
                            | ((unsigned)(unsigned short)f2bf(xv.y) << 16);
                __hip_atomic_store((unsigned*)(ring + (size_t)(sp & 7) * 65536
                                               + (size_t)(bg0 + rl) * 1024 + col),
                                   pk, __ATOMIC_RELAXED, __HIP_MEMORY_SCOPE_AGENT);
            }
        }

        if (w >= 2 && t > 0) {
            const unsigned tgt = (unsigned)(t + 1);
            const unsigned* f0 = flags + g * 128 + l;
            const unsigned* f1 = f0 + 64;
            while (aldu32(f0) < tgt || aldu32(f1) < tgt) __builtin_amdgcn_s_sleep(1);
        }
        asm volatile("" ::: "memory");

        f32x4 acc[2][2] = {};
        if (RING || w >= 2) {
            const unsigned short* src;
            int colb;
            if (w < 2) { src = ring + (size_t)(t & 7) * 65536; colb = wb; }
            else       { src = hcur;                           colb = wb - 1024; }
#pragma unroll
            for (int half = 0; half < 2; ++half) {
                unsigned long long stg[8][2][2];
#pragma unroll
                for (int k8 = 0; k8 < 8; ++k8) {
                    const int ks = half * 8 + k8;
#pragma unroll
                    for (int mt = 0; mt < 2; ++mt) {
                        const unsigned short* p = src + (size_t)(bg0 + mt * 16 + lm) * 1024
                                                  + colb + ks * 32 + lk * 8;
                        stg[k8][mt][0] = ald64(p);
                        stg[k8][mt][1] = ald64(p + 4);
                    }
                }
#pragma unroll
                for (int k8 = 0; k8 < 8; ++k8) {
                    const int ks = half * 8 + k8;
#pragma unroll
                    for (int mt = 0; mt < 2; ++mt) {
                        struct { unsigned long long a, b; } u{stg[k8][mt][0], stg[k8][mt][1]};
                        bf16x8 af = __builtin_bit_cast(bf16x8, u);
                        acc[mt][0] = __builtin_amdgcn_mfma_f32_16x16x32_bf16(af, bfr[0][ks], acc[mt][0], 0, 0, 0);
                        acc[mt][1] = __builtin_amdgcn_mfma_f32_16x16x32_bf16(af, bfr[1][ks], acc[mt][1], 0, 0, 0);
                    }
                }
            }
        } else {
#pragma unroll
            for (int ks = 0; ks < 16; ++ks) {
#pragma unroll
                for (int mt = 0; mt < 2; ++mt) {
                    const size_t row = (size_t)(bg0 + mt * 16 + lm);
                    const size_t off = (row * Tt + t) * Dd + wb + ks * 32 + lk * 8;
                    float4 a = *(const float4*)(x + off);
                    float4 b = *(const float4*)(x + off + 4);
                    bf16x8 af = pack8(a, b);
                    acc[mt][0] = __builtin_amdgcn_mfma_f32_16x16x32_bf16(af, bfr[0][ks], acc[mt][0], 0, 0, 0);
                    acc[mt][1] = __builtin_amdgcn_mfma_f32_16x16x32_bf16(af, bfr[1][ks], acc[mt][1], 0, 0, 0);
                }
            }
        }

#pragma unroll
        for (int mt = 0; mt < 2; ++mt)
#pragma unroll
            for (int nt = 0; nt < 2; ++nt) {
                const int n = nt * 16 + lm;
                if (n < 24) {
#pragma unroll
                    for (int i = 0; i < 4; ++i)
                        comb[w][mt * 16 + lk * 4 + i][n] = acc[mt][nt][i];
                }
            }
        __syncthreads();

        {
            const int b = tid >> 3, j = tid & 7;
            const float rz = comb[0][b][j] + comb[1][b][j] + comb[2][b][j] + comb[3][b][j]
                             + bxv[j] + bhv[j];
            const float uz = comb[0][b][8 + j] + comb[1][b][8 + j] + comb[2][b][8 + j]
                             + comb[3][b][8 + j] + bxv[8 + j] + bhv[8 + j];
            const float nx = comb[0][b][16 + j] + comb[1][b][16 + j] + bxv[16 + j];
            const float nh = comb[2][b][16 + j] + comb[3][b][16 + j] + bhv[16 + j];
            const float r  = 1.0f / (1.0f + __expf(-rz));
            const float u  = 1.0f / (1.0f + __expf(-uz));
            const float zz = nx + r * nh;
            const float e2 = __expf(2.0f * zz);
            const float nv = 1.0f - 2.0f / (e2 + 1.0f);
            const float hold = hp[b][j];
            const float hy = u * hold + (1.0f - u) * nv;
            hp[b][j] = hy;
            unsigned short* hn = hbuf + (size_t)((t + 1) & 1) * Bb * Hh
                                 + (size_t)(bg0 + b) * 1024 + j0 + j;
            __hip_atomic_store(hn, (unsigned short)f2bf(hy), __ATOMIC_RELAXED,
                               __HIP_MEMORY_SCOPE_AGENT);
            if (t == Tt - 1) hfinal[(size_t)(bg0 + b) * 1024 + j0 + j] = hy;
        }
        asm volatile("s_waitcnt vmcnt(0)" ::: "memory");
        __syncthreads();
        if (tid == 0 && t + 1 < Tt)
            __hip_atomic_store(&flags[g * 128 + c], (unsigned)(t + 2), __ATOMIC_RELAXED,
                               __HIP_MEMORY_SCOPE_AGENT);
    }
}

// ---------------- final projection + log_softmax ------------------------------
__global__ __launch_bounds__(1024)
void final_kernel(const float* __restrict__ hfinal, const float* __restrict__ Wf,
                  const float* __restrict__ bfv, float* __restrict__ out) {
    const int b = blockIdx.x;
    const int o = threadIdx.x;
    __shared__ float hs[1024];
    __shared__ float redm[16], redsum[16], bcast[2];
    hs[o] = hfinal[(size_t)b * 1024 + o];
    __syncthreads();

    const float* wr = Wf + (size_t)o * 1024;
    float acc = bfv[o];
#pragma unroll 4
    for (int k = 0; k < 1024; k += 4) {
        float4 wv = *(const float4*)(wr + k);
        acc += hs[k] * wv.x + hs[k + 1] * wv.y + hs[k + 2] * wv.z + hs[k + 3] * wv.w;
    }

    float m = acc;
#pragma unroll
    for (int off = 32; off > 0; off >>= 1) m = fmaxf(m, __shfl_xor(m, off));
    if ((o & 63) == 0) redm[o >> 6] = m;
    __syncthreads();
    if (o == 0) {
        float mm = redm[0];
#pragma unroll
        for (int i = 1; i < 16; ++i) mm = fmaxf(mm, redm[i]);
        bcast[0] = mm;
    }
    __syncthreads();
    const float bm = bcast[0];
    float s = __expf(acc - bm);
#pragma unroll
    for (int off = 32; off > 0; off >>= 1) s += __shfl_xor(s, off);
    if ((o & 63) == 0) redsum[o >> 6] = s;
    __syncthreads();
    if (o == 0) {
        float ss = 0.0f;
        for (int i = 0; i < 16; ++i) ss += redsum[i];
        bcast[1] = logf(ss);
    }
    __syncthreads();
    out[(size_t)b * 1024 + o] = acc - bm - bcast[1];
}

// ---------------- launch ------------------------------------------------------
extern "C" void kernel_launch(void* const* d_in, const int* in_sizes, int n_in,
                              void* d_out, int out_size, void* d_ws, size_t ws_size,
                              hipStream_t stream) {
    (void)in_sizes; (void)n_in; (void)out_size;
    const float* x   = (const float*)d_in[0];
    const float* Wx  = (const float*)d_in[1];
    const float* bx  = (const float*)d_in[2];
    const float* Wh  = (const float*)d_in[3];
    const float* bh  = (const float*)d_in[4];
    const float* Wf  = (const float*)d_in[5];
    const float* bfv = (const float*)d_in[6];
    float* out = (float*)d_out;
    char* ws = (char*)d_ws;

    // Common Path-A prefix
    const size_t HL = 1024;                     // hl2:   256 KB
    const size_t HM = HL + 262144;              // hmall: 256 KB
    const size_t HS = HM + 262144;              // hstate fp32 256 KB
    const size_t HF = HS + 262144;              // hfinal fp32 256 KB
    const size_t WX = HF + 262144;              // Wx bf16 6 MB
    const size_t XB = WX + 6291456;             // xb: 64x2048x1024 bf16 = 256 MB (path A+)
    const size_t XB_BYTES = (size_t)Bb * Tt * Dd * 2;
    const size_t XP_A  = WX + 6291456;          // xp offset without xb (r13 path)
    const size_t XP_AB = XB + XB_BYTES;         // xp offset with xb

    // choose path: A+ (xb) needs XP_AB + >=32 windows of xp
    long Wab = 0, Wa = 0;
    if (ws_size > XP_AB) Wab = (long)((ws_size - XP_AB) / 393216);
    if (ws_size > XP_A)  Wa  = (long)((ws_size - XP_A) / 393216);
    if (Wab > 2048) Wab = 2048;
    if (Wa  > 2048) Wa  = 2048;

    if (Wab >= 32) {
        // ---- Path A+: bf16 x, MALL-resident ----
        unsigned short* hl2   = (unsigned short*)(ws + HL);
        unsigned short* hmall = (unsigned short*)(ws + HM);
        float* hstate         = (float*)(ws + HS);
        float* hfinal         = (float*)(ws + HF);
        unsigned short* Wxb   = (unsigned short*)(ws + WX);
        unsigned short* xbuf  = (unsigned short*)(ws + XB);
        unsigned short* xp    = (unsigned short*)(ws + XP_AB);
        const int W = (int)Wab;

        hipMemsetAsync(ws + HL, 0x00, 131072, stream);
        hipMemsetAsync(ws + HL + 131072, 0xFF, 131072, stream);
        hipMemsetAsync(ws + HM, 0x00, 131072, stream);
        hipMemsetAsync(ws + HM + 131072, 0xFF, 131072, stream);
        hipMemsetAsync(ws + HS, 0x00, 262144, stream);
        wcvt<<<1536, 256, 0, stream>>>(Wx, (unsigned short*)Wxb, 3L * 1024 * 1024);
        wcvt<<<2048, 256, 0, stream>>>(x, xbuf, (long)Bb * Tt * Dd);
        for (int t0 = 0; t0 < Tt; t0 += W) {
            const int Wc = (Tt - t0 < W) ? (Tt - t0) : W;
            xp_gemm4<<<dim3(24, Wc), 256, 0, stream>>>(xbuf, Wxb, xp, t0);
            gru_scan6<<<256, 512, 0, stream>>>(Wh, bx, bh, hl2, hmall, hstate,
                                               hfinal, xp, t0, t0 + Wc);
        }
        final_kernel<<<64, 1024, 0, stream>>>(hfinal, Wf, bfv, out);
    } else if (Wa >= 32) {
        // ---- Path A (r13): fp32 x ----
        unsigned short* hl2   = (unsigned short*)(ws + HL);
        unsigned short* hmall = (unsigned short*)(ws + HM);
        float* hstate         = (float*)(ws + HS);
        float* hfinal         = (float*)(ws + HF);
        unsigned short* Wxb   = (unsigned short*)(ws + WX);
        unsigned short* xp    = (unsigned short*)(ws + XP_A);
        const int W = (int)Wa;

        hipMemsetAsync(ws + HL, 0x00, 131072, stream);
        hipMemsetAsync(ws + HL + 131072, 0xFF, 131072, stream);
        hipMemsetAsync(ws + HM, 0x00, 131072, stream);
        hipMemsetAsync(ws + HM + 131072, 0xFF, 131072, stream);
        hipMemsetAsync(ws + HS, 0x00, 262144, stream);
        wcvt<<<1536, 256, 0, stream>>>(Wx, (unsigned short*)Wxb, 3L * 1024 * 1024);
        for (int t0 = 0; t0 < Tt; t0 += W) {
            const int Wc = (Tt - t0 < W) ? (Tt - t0) : W;
            xp_gemm3<<<dim3(24, Wc), 256, 0, stream>>>(x, Wxb, xp, t0);
            gru_scan6<<<256, 512, 0, stream>>>(Wh, bx, bh, hl2, hmall, hstate,
                                               hfinal, xp, t0, t0 + Wc);
        }
        final_kernel<<<64, 1024, 0, stream>>>(hfinal, Wf, bfv, out);
    } else {
        // ---- round-2 fallback ----
        unsigned* flags      = (unsigned*)ws;                                  // 1 KB
        unsigned short* hbuf = (unsigned short*)(ws + 1024);                   // 256 KB
        float* hfinal        = (float*)(ws + 1024 + 262144);                   // 256 KB
        unsigned short* ring = (unsigned short*)(ws + 1024 + 262144 + 262144); // 1 MB
        const size_t need_ring = 1024 + 262144 + 262144 + (size_t)8 * 131072;
        const bool use_ring = (ws_size >= need_ring);

        hipMemsetAsync(d_ws, 0, 1024 + (size_t)Bb * Hh * 2, stream);
        if (use_ring)
            gru_scan<true><<<256, 256, 0, stream>>>(x, Wx, bx, Wh, bh, hbuf, hfinal, ring, flags);
        else
            gru_scan<false><<<256, 256, 0, stream>>>(x, Wx, bx, Wh, bh, hbuf, hfinal, ring, flags);
        final_kernel<<<64, 1024, 0, stream>>>(hfinal, Wf, bfv, out);
    }
}